// Round 18
// baseline (434.706 us; speedup 1.0000x reference)
//
#include <hip/hip_runtime.h>
#include <hip/hip_bf16.h>
#include <cstdint>
#include <cstddef>

using u16 = unsigned short;
typedef __attribute__((ext_vector_type(4))) float f32x4;
typedef __attribute__((ext_vector_type(8))) short bf16x8;
typedef __attribute__((ext_vector_type(4))) short bf16x4;

constexpr int Bc = 4, Tc = 1024, TMc = 1024, Dc = 1024, Hc = 16, HSc = 64, FFc = 4096;
constexpr int BT = Bc * Tc;  // 4096 rows
constexpr float C2 = 0.18033688f;   // 0.125 * log2(e) — softmax in exp2 domain

struct Ptr4 { u16* p0; u16* p1; u16* p2; u16* p3; };
struct P8f  { const float* p[8]; };
struct P8u  { u16* p[8]; };

__device__ __forceinline__ u16 f2bf(float f) {
  union { float f; uint32_t u; } v; v.f = f;
  uint32_t u = v.u;
  u += 0x7fffu + ((u >> 16) & 1u);   // RNE (finite inputs only)
  return (u16)(u >> 16);
}
__device__ __forceinline__ float b2f(u16 u) {
  union { float f; uint32_t u32; } v; v.u32 = (uint32_t)u << 16; return v.f;
}
// pack two floats' high halves (truncating bf16 pair) in ONE v_perm_b32
__device__ __forceinline__ uint32_t pk2(float hi, float lo) {
  union { float f; uint32_t u; } a, b; a.f = hi; b.f = lo;
  return __builtin_amdgcn_perm(a.u, b.u, 0x07060302u);
}

__device__ __forceinline__ bf16x8 cat8(bf16x4 lo, bf16x4 hi) {
  bf16x8 r;
  r[0] = lo[0]; r[1] = lo[1]; r[2] = lo[2]; r[3] = lo[3];
  r[4] = hi[0]; r[5] = hi[1]; r[6] = hi[2]; r[7] = hi[3];
  return r;
}

// async global->LDS, 16B per lane; LDS dest = wave-uniform base + lane*16B (linear)
__device__ __forceinline__ void gload16(const u16* g, u16* l) {
  __builtin_amdgcn_global_load_lds((const __attribute__((address_space(1))) void*)g,
                                   (__attribute__((address_space(3))) void*)l, 16, 0, 0);
}

// ---------------- transpose + fp32->bf16 convert: 8x [1024,1024] in one launch.
// Grid (16,16,8); blockIdx.z selects src/dst (q,k,v land directly in wqkvT).
__global__ __launch_bounds__(256)
void tconv8(P8f S, P8u D)
{
  __shared__ u16 tile[64][65];
  const float* in = S.p[blockIdx.z];
  u16* outp = D.p[blockIdx.z];
  const int tx = threadIdx.x & 15, ty = threadIdx.x >> 4;
  const int kb = blockIdx.y * 64, nb = blockIdx.x * 64;
  #pragma unroll
  for (int i = 0; i < 4; ++i) {
    const int r = ty + i * 16;
    const float4 v = *(const float4*)(in + (size_t)(kb + r) * Dc + nb + tx * 4);
    tile[r][tx * 4 + 0] = f2bf(v.x);
    tile[r][tx * 4 + 1] = f2bf(v.y);
    tile[r][tx * 4 + 2] = f2bf(v.z);
    tile[r][tx * 4 + 3] = f2bf(v.w);
  }
  __syncthreads();
  #pragma unroll
  for (int i = 0; i < 4; ++i) {
    const int n = ty + i * 16;
    bf16x4 o;
    o[0] = (short)tile[tx * 4 + 0][n];
    o[1] = (short)tile[tx * 4 + 1][n];
    o[2] = (short)tile[tx * 4 + 2][n];
    o[3] = (short)tile[tx * 4 + 3][n];
    *(bf16x4*)(outp + (size_t)(nb + n) * Dc + kb + tx * 4) = o;
  }
}

// ---------------- transpose + convert, general shape (w1, w2)
__global__ __launch_bounds__(256)
void tconv(const float* __restrict__ in, u16* __restrict__ outp, int K, int N)
{
  __shared__ u16 tile[64][65];
  const int tx = threadIdx.x & 15, ty = threadIdx.x >> 4;
  const int kb = blockIdx.y * 64, nb = blockIdx.x * 64;
  #pragma unroll
  for (int i = 0; i < 4; ++i) {
    const int r = ty + i * 16;
    const float4 v = *(const float4*)(in + (size_t)(kb + r) * N + nb + tx * 4);
    tile[r][tx * 4 + 0] = f2bf(v.x);
    tile[r][tx * 4 + 1] = f2bf(v.y);
    tile[r][tx * 4 + 2] = f2bf(v.z);
    tile[r][tx * 4 + 3] = f2bf(v.w);
  }
  __syncthreads();
  #pragma unroll
  for (int i = 0; i < 4; ++i) {
    const int n = ty + i * 16;
    bf16x4 o;
    o[0] = (short)tile[tx * 4 + 0][n];
    o[1] = (short)tile[tx * 4 + 1][n];
    o[2] = (short)tile[tx * 4 + 2][n];
    o[3] = (short)tile[tx * 4 + 3][n];
    *(bf16x4*)(outp + (size_t)(nb + n) * K + kb + tx * 4) = o;
  }
}

// ---------------- elementwise fp32 -> bf16
__global__ __launch_bounds__(256)
void cvt_bf16(const float* __restrict__ in, u16* __restrict__ outp, int n4)
{
  const int i = blockIdx.x * 256 + threadIdx.x;
  if (i < n4) {
    const float4 v = ((const float4*)in)[i];
    bf16x4 o;
    o[0] = (short)f2bf(v.x); o[1] = (short)f2bf(v.y);
    o[2] = (short)f2bf(v.z); o[3] = (short)f2bf(v.w);
    ((bf16x4*)outp)[i] = o;
  }
}

// ---------------- bias concats (replaces 5 hipMemcpyAsync graph nodes)
__global__ __launch_bounds__(1024)
void biascat(float* __restrict__ bqkv, float* __restrict__ bkv,
             const float* b0, const float* b1, const float* b2,
             const float* b5, const float* b6)
{
  const int t = threadIdx.x, z = blockIdx.x;
  if (z < 3) {
    const float* s = (z == 0) ? b0 : (z == 1) ? b1 : b2;
    bqkv[z * 1024 + t] = s[t];
  } else {
    const float* s = (z == 3) ? b5 : b6;
    bkv[(z - 3) * 1024 + t] = s[t];
  }
}

// ---------------- GEMM: C[M,N] = A[M,K](bf16) * Bt[N,K](bf16)^T + bias
// Both-sides XOR swizzle + (DEPTH+1)-buffer counted-vmcnt pipeline + XCD-chunked
// grouped-M remap. bf16 outputs use the per-wave LDS-staged coalesced epilogue.
// MODE 0: out bf16; MODE 1: out f32 + resid; MODE 2: out bf16 + relu;
// MODE 3: split-K bf16 partial — blockIdx.y = sk, K-chunk Kch, out -> P.p[sk].
template<int MODE, int BMv, int DEPTH>
__global__ __launch_bounds__((BMv == 256) ? 512 : 256)
void gemm_bt(const u16* __restrict__ A, const u16* __restrict__ Bt,
             const float* __restrict__ bias, const float* __restrict__ resid,
             void* __restrict__ outp, int M, int N, int K, int Kch, Ptr4 P)
{
  constexpr int BM = BMv, BN = 128, BK = 32;
  constexpr int NTHR = (BM == 256) ? 512 : 256;
  constexpr int RPC = NTHR / 4;               // rows covered per gload16 call
  constexpr int ACALLS = BM / RPC;            // 2
  constexpr int BCALLS = BN / RPC;            // 1 (wide) or 2 (narrow)
  constexpr int CALLS = ACALLS + BCALLS;      // 3 (wide) or 4 (narrow)
  constexpr int NB = DEPTH + 1;
  __shared__ __align__(16) u16 As[NB][BM * BK];
  __shared__ __align__(16) u16 Bs[NB][BN * BK];
  const int tid = threadIdx.x;
  const int lane = tid & 63, w = tid >> 6;
  const int wr = w >> 1, wc = w & 1;
  const int hi4 = lane >> 4, lr = lane & 15;

  // --- XCD-chunked grouped block remap (requires nwg%8==0 and (M/BM)%8==0)
  const int nwg = gridDim.x;
  const int GX = N / BN;
  const int bid0 = (int)blockIdx.x;
  const int L = (bid0 & 7) * (nwg >> 3) + (bid0 >> 3);
  const int bandw = 8 * GX;
  const int band = L / bandw;
  const int rem = L - band * bandw;
  const int m0 = (band * 8 + (rem & 7)) * BM;
  const int n0 = (rem >> 3) * BN;

  const int k0 = (MODE == 3) ? (int)blockIdx.y * Kch : 0;

  // staging: row = tid>>2, 16B slot = tid&3 (LDS linear);
  // source slot pre-swizzled: LDS slot s of row r holds global slot s^((r>>1)&3).
  const int srow = tid >> 2;
  const int gslot = (tid & 3) ^ ((srow >> 1) & 3);
  const u16* ga = A  + (size_t)(m0 + srow) * K + k0 + gslot * 8;
  const u16* gb = Bt + (size_t)(n0 + srow) * K + k0 + gslot * 8;
  const int wofs = w * 512;
  const int cswz = (lr >> 1) & 3;             // (row>>1)&3 for read rows base+lr

  auto stage = [&](int buf, int kt) {
    #pragma unroll
    for (int j = 0; j < ACALLS; ++j)
      gload16(ga + (size_t)j * RPC * K + kt, &As[buf][j * NTHR * 8 + wofs]);
    #pragma unroll
    for (int j = 0; j < BCALLS; ++j)
      gload16(gb + (size_t)j * RPC * K + kt, &Bs[buf][j * NTHR * 8 + wofs]);
  };

  f32x4 acc[4][4] = {};
  const int nt = Kch / BK;

  #pragma unroll
  for (int p = 0; p < DEPTH; ++p)
    if (p < nt) stage(p % NB, p * BK);

  int cur = 0;
  for (int t = 0; t < nt; ++t) {
    // allowed outstanding after wait = min(DEPTH-1, nt-1-t) * CALLS  (tail-correct)
    {
      const int ahead = nt - 1 - t;
      const int cap = (ahead < DEPTH - 1 ? ahead : DEPTH - 1) * CALLS;
      switch (cap) {
        case 0:  asm volatile("s_waitcnt vmcnt(0)"  ::: "memory"); break;
        case 3:  asm volatile("s_waitcnt vmcnt(3)"  ::: "memory"); break;
        case 4:  asm volatile("s_waitcnt vmcnt(4)"  ::: "memory"); break;
        case 8:  asm volatile("s_waitcnt vmcnt(8)"  ::: "memory"); break;
        default: asm volatile("s_waitcnt vmcnt(12)" ::: "memory"); break;
      }
    }
    __builtin_amdgcn_s_barrier();
    __builtin_amdgcn_sched_barrier(0);

    if (t + DEPTH < nt) {
      int b2 = cur + DEPTH; if (b2 >= NB) b2 -= NB;
      stage(b2, (t + DEPTH) * BK);
    }

    bf16x8 af[4], bfr[4];
    #pragma unroll
    for (int mb = 0; mb < 4; ++mb)
      af[mb] = *(const bf16x8*)&As[cur][(wr * 64 + mb * 16 + lr) * BK + (hi4 ^ cswz) * 8];
    #pragma unroll
    for (int nb = 0; nb < 4; ++nb)
      bfr[nb] = *(const bf16x8*)&Bs[cur][(wc * 64 + nb * 16 + lr) * BK + (hi4 ^ cswz) * 8];
    #pragma unroll
    for (int mb = 0; mb < 4; ++mb)
      #pragma unroll
      for (int nb = 0; nb < 4; ++nb)
        acc[mb][nb] = __builtin_amdgcn_mfma_f32_16x16x32_bf16(af[mb], bfr[nb], acc[mb][nb], 0, 0, 0);

    ++cur; if (cur == NB) cur = 0;
  }

  const int orow = m0 + wr * 64 + 4 * hi4;
  const int ocol = n0 + wc * 64 + lr;

  if (MODE == 1) {
    #pragma unroll
    for (int nb = 0; nb < 4; ++nb) {
      const int c = ocol + nb * 16;
      const float bv = bias ? bias[c] : 0.0f;
      #pragma unroll
      for (int mb = 0; mb < 4; ++mb) {
        #pragma unroll
        for (int r = 0; r < 4; ++r) {
          const size_t idx = (size_t)(orow + mb * 16 + r) * N + c;
          ((float*)outp)[idx] = acc[mb][nb][r] + bv + resid[idx];
        }
      }
    }
  } else {
    // bf16 epilogue: per-wave LDS strip (16x68 u16) in Bs, coalesced 16B stores.
    __syncthreads();                     // all waves done with pipeline LDS reads
    u16* eb = &Bs[0][0] + w * 1088;      // 16*68 = 1088 u16 per wave (8*1088 <= 12288)
    u16* pout_;
    if (MODE == 3) {
      const int sk = blockIdx.y;
      pout_ = (sk == 0) ? P.p0 : (sk == 1) ? P.p1 : (sk == 2) ? P.p2 : P.p3;
    } else {
      pout_ = (u16*)outp;
    }
    const int r2 = lane >> 3;            // 0..7
    const int c2 = (lane & 7) * 8;       // 16B chunk
    #pragma unroll
    for (int mb = 0; mb < 4; ++mb) {
      #pragma unroll
      for (int nb = 0; nb < 4; ++nb) {
        const int c = ocol + nb * 16;
        const float bv = (MODE != 3 && bias) ? bias[c] : 0.0f;
        #pragma unroll
        for (int r = 0; r < 4; ++r) {
          float v = acc[mb][nb][r] + bv;
          if (MODE == 2) v = fmaxf(v, 0.0f);
          eb[(4 * hi4 + r) * 68 + nb * 16 + lr] = f2bf(v);
        }
      }
      // same-wave DS ops are in-order; read back coalesced and store full sectors
      #pragma unroll
      for (int pass = 0; pass < 2; ++pass) {
        const int rr = pass * 8 + r2;
        const bf16x8 vv = *(const bf16x8*)&eb[rr * 68 + c2];
        *(bf16x8*)&pout_[(size_t)(m0 + wr * 64 + mb * 16 + rr) * N + n0 + wc * 64 + c2] = vv;
      }
    }
  }
}

// ---------------- flash attention, swapped QK^T. 1D grid (1024 blocks), R18:
// XCD-chunked remap so all 16 q-tiles of 8 consecutive (b,h) groups land on the
// same XCD — K/V footprint 8 x 512KB = 2MB <= per-XCD L2, turning the 16x
// K/V re-read into L2 hits (FETCH was ~3x unique working set).
// Double-buffered K/V LDS with T14 async split; V write vectorized + XOR swizzle;
// T13 defer-max; exp2-domain softmax; v_perm P pack.
__global__ __launch_bounds__(256)
void flash_attn(const u16* __restrict__ Q, const u16* __restrict__ Kb,
                const u16* __restrict__ Vb, u16* __restrict__ Y,
                float* __restrict__ Mout, float* __restrict__ Lout,
                int qstr, int kstr)
{
  constexpr int LDK = 72;
  __shared__ __align__(16) u16 Ks[2][64 * LDK];   // [key][hs]
  __shared__ __align__(16) u16 Vt[2][64 * LDK];   // [d][key ^ swz]
  const int tid = threadIdx.x, lane = tid & 63, w = tid >> 6;
  const int hi4 = lane >> 4, lr = lane & 15;
  // XCD-chunked remap: nwg=1024; chunk of 128 per XCD = 8 bh-groups x 16 qt
  const int bid0 = (int)blockIdx.x;
  const int L = (bid0 & 7) * 128 + (bid0 >> 3);
  const int bh = L >> 4, qt = L & 15;
  const int b = bh >> 4, h = bh & 15;
  const int q0 = qt * 64 + w * 16;

  bf16x8 qf[2];
  {
    const u16* qp = Q + ((size_t)(b * Tc + q0 + lr)) * qstr + h * HSc;
    #pragma unroll
    for (int ks = 0; ks < 2; ++ks)
      qf[ks] = cat8(*(const bf16x4*)(qp + ks * 32 + 4 * hi4),
                    *(const bf16x4*)(qp + ks * 32 + 16 + 4 * hi4));
  }

  float m_run = -1e30f, l_run = 0.0f;   // m_run in log2 domain
  f32x4 o[4] = {};  // O[q=4*hi4+r][d = nb*16+lr]

  const int krow = tid >> 3, kcol = (tid & 7) * 8;
  const int s4 = (tid >> 4) * 4;     // 4 consecutive keys per thread
  const int d4 = (tid & 15) * 4;     // 4 consecutive d per thread (coalesced loads)

  const u16* kbase = Kb + ((size_t)(b * TMc + krow)) * kstr + h * HSc + kcol;
  const u16* vbase = Vb + ((size_t)(b * TMc + s4)) * kstr + h * HSc + d4;

  bf16x8 kreg0, kreg1;
  bf16x4 vreg[4];

  auto loadch = [&](int s0) {
    const u16* kp = kbase + (size_t)s0 * kstr;
    kreg0 = *(const bf16x8*)kp;
    kreg1 = *(const bf16x8*)(kp + (size_t)32 * kstr);
    const u16* vp = vbase + (size_t)s0 * kstr;
    #pragma unroll
    for (int j = 0; j < 4; ++j)
      vreg[j] = *(const bf16x4*)(vp + (size_t)j * kstr);
  };
  auto writech = [&](int buf) {
    *(bf16x8*)&Ks[buf][krow * LDK + kcol]        = kreg0;
    *(bf16x8*)&Ks[buf][(krow + 32) * LDK + kcol] = kreg1;
    #pragma unroll
    for (int i = 0; i < 4; ++i) {
      bf16x4 tr;
      tr[0] = vreg[0][i]; tr[1] = vreg[1][i]; tr[2] = vreg[2][i]; tr[3] = vreg[3][i];
      *(bf16x4*)&Vt[buf][(d4 + i) * LDK + (s4 ^ d4)] = tr;
    }
  };

  loadch(0);
  writech(0);

  constexpr int NT = TMc / 64;
  for (int t = 0; t < NT; ++t) {
    const int cur = t & 1;
    __syncthreads();                       // buf[cur] fully written by all waves
    if (t + 1 < NT) loadch((t + 1) * 64);  // global loads in flight during compute

    // St = K * Q^T -> St[key = kb2*16 + 4*hi4 + r][q = lr]
    f32x4 st[4];
    #pragma unroll
    for (int kb2 = 0; kb2 < 4; ++kb2) {
      f32x4 a = {};
      #pragma unroll
      for (int ks = 0; ks < 2; ++ks) {
        const u16* p = &Ks[cur][(kb2 * 16 + lr) * LDK + ks * 32 + 4 * hi4];
        bf16x8 kf = cat8(*(const bf16x4*)p, *(const bf16x4*)(p + 16));
        a = __builtin_amdgcn_mfma_f32_16x16x32_bf16(kf, qf[ks], a, 0, 0, 0);
      }
      st[kb2] = a;
    }

    float cmax = -1e30f;
    #pragma unroll
    for (int kb2 = 0; kb2 < 4; ++kb2) {
      #pragma unroll
      for (int r = 0; r < 4; ++r) st[kb2][r] *= C2;   // exp2-domain logits
      cmax = fmaxf(cmax, fmaxf(fmaxf(st[kb2][0], st[kb2][1]),
                               fmaxf(st[kb2][2], st[kb2][3])));
    }
    cmax = fmaxf(cmax, __shfl_xor(cmax, 16));
    cmax = fmaxf(cmax, __shfl_xor(cmax, 32));

    // T13 defer-max (THR = 8 nats = 11.5416 in log2 domain), wave-uniform
    const bool need = !__all(cmax - m_run <= 11.5416f);
    float m_new = m_run, sc = 1.0f;
    if (need) {
      m_new = fmaxf(m_run, cmax);
      sc = exp2f(m_run - m_new);
    }
    float psum = 0.0f;
    #pragma unroll
    for (int kb2 = 0; kb2 < 4; ++kb2)
      #pragma unroll
      for (int r = 0; r < 4; ++r) {
        const float e = exp2f(st[kb2][r] - m_new);
        st[kb2][r] = e;
        psum += e;
      }
    psum += __shfl_xor(psum, 16);
    psum += __shfl_xor(psum, 32);
    if (need) {
      l_run = l_run * sc + psum;
      #pragma unroll
      for (int r = 0; r < 4; ++r) {
        const float osc = __shfl(sc, 4 * hi4 + r);
        #pragma unroll
        for (int nb = 0; nb < 4; ++nb) o[nb][r] *= osc;
      }
    } else {
      l_run += psum;
    }
    m_run = m_new;

    bf16x8 pa[2];
    #pragma unroll
    for (int ks = 0; ks < 2; ++ks) {
      union { bf16x8 v; uint32_t u[4]; } pw;
      pw.u[0] = pk2(st[2 * ks + 0][1], st[2 * ks + 0][0]);
      pw.u[1] = pk2(st[2 * ks + 0][3], st[2 * ks + 0][2]);
      pw.u[2] = pk2(st[2 * ks + 1][1], st[2 * ks + 1][0]);
      pw.u[3] = pk2(st[2 * ks + 1][3], st[2 * ks + 1][2]);
      pa[ks] = pw.v;
    }
    #pragma unroll
    for (int nb = 0; nb < 4; ++nb) {
      const int row = nb * 16 + lr;
      const int g = 4 * (row >> 2);
      #pragma unroll
      for (int ks = 0; ks < 2; ++ks) {
        const int c0 = (ks * 32 + 4 * hi4) ^ g;
        const int c1 = (ks * 32 + 16 + 4 * hi4) ^ g;
        bf16x8 vf = cat8(*(const bf16x4*)&Vt[cur][row * LDK + c0],
                         *(const bf16x4*)&Vt[cur][row * LDK + c1]);
        o[nb] = __builtin_amdgcn_mfma_f32_16x16x32_bf16(pa[ks], vf, o[nb], 0, 0, 0);
      }
    }

    if (t + 1 < NT) writech(cur ^ 1);      // lands before next barrier
  }

  #pragma unroll
  for (int r = 0; r < 4; ++r) {
    const float li = 1.0f / __shfl(l_run, 4 * hi4 + r);
    const size_t yr = ((size_t)(b * Tc + q0 + 4 * hi4 + r)) * Dc + h * HSc;
    #pragma unroll
    for (int nb = 0; nb < 4; ++nb)
      Y[yr + nb * 16 + lr] = f2bf(o[nb][r] * li);
  }
  if (Mout != nullptr && lane < 16) {
    Mout[(size_t)bh * Tc + q0 + lr] = m_run;   // log2-domain
    Lout[(size_t)bh * Tc + q0 + lr] = l_run;
  }
}

// ---------------- cross-attn prob average over heads.
// Grid: (TMc/64, Tc/64, Bc) — 1024 blocks; double-buffered async K staging +
// both-sides XOR swizzle. mws holds log2-domain maxima.
__global__ __launch_bounds__(256)
void attn_avg(const u16* __restrict__ Q, const u16* __restrict__ Kb,
              const float* __restrict__ Mws, const float* __restrict__ Lws,
              float* __restrict__ outp, int qstr, int kstr)
{
  __shared__ __align__(16) u16 Ks[2][64 * 64];
  __shared__ __align__(16) float avg[64 * 68];
  const int tid = threadIdx.x, lane = tid & 63, w = tid >> 6;
  const int hi4 = lane >> 4, lr = lane & 15;
  const int b = blockIdx.z, qt = blockIdx.y, scn = blockIdx.x;
  const int q0 = qt * 64 + w * 16;
  const int s0 = scn * 64;

  const int srow = w * 8 + (lane >> 3);
  const int scol = ((lane & 7) ^ (lane >> 3)) * 8;
  const u16* kg = Kb + ((size_t)(b * TMc + s0 + srow)) * kstr + scol;
  const size_t skip32 = (size_t)32 * kstr;

  auto stage = [&](int buf, int h) {
    const u16* g = kg + h * HSc;
    gload16(g,          &Ks[buf][w * 512]);
    gload16(g + skip32, &Ks[buf][2048 + w * 512]);
  };

  float acc[4][4] = {};
  const int rsw = lr & 7;

  stage(0, 0);
  #pragma unroll 1
  for (int h = 0; h < Hc; ++h) {
    const int cur = h & 1;
    __syncthreads();
    if (h + 1 < Hc) stage(cur ^ 1, h + 1);

    const u16* qp = Q + ((size_t)(b * Tc + q0 + lr)) * qstr + h * HSc;
    const bf16x8 qf0 = *(const bf16x8*)(qp + 8 * hi4);
    const bf16x8 qf1 = *(const bf16x8*)(qp + 32 + 8 * hi4);
    const float mh2 = Mws[(size_t)(b * Hc + h) * Tc + q0 + lr];   // log2-domain
    const float li = 1.0f / Lws[(size_t)(b * Hc + h) * Tc + q0 + lr];

    #pragma unroll
    for (int kb2 = 0; kb2 < 4; ++kb2) {
      const int row = kb2 * 16 + lr;
      const bf16x8 kf0 = *(const bf16x8*)&Ks[cur][row * 64 + ((hi4     ) ^ rsw) * 8];
      const bf16x8 kf1 = *(const bf16x8*)&Ks[cur][row * 64 + ((hi4 + 4) ^ rsw) * 8];
      f32x4 a = {};
      a = __builtin_amdgcn_mfma_f32_16x16x32_bf16(kf0, qf0, a, 0, 0, 0);
      a = __builtin_amdgcn_mfma_f32_16x16x32_bf16(kf1, qf1, a, 0, 0, 0);
      #pragma unroll
      for (int r = 0; r < 4; ++r)
        acc[kb2][r] += exp2f(a[r] * C2 - mh2) * li;
    }
  }

  __syncthreads();
  #pragma unroll
  for (int kb2 = 0; kb2 < 4; ++kb2)
    #pragma unroll
    for (int r = 0; r < 4; ++r)
      avg[(w * 16 + lr) * 68 + kb2 * 16 + 4 * hi4 + r] = acc[kb2][r] * (1.0f / Hc);
  __syncthreads();
  const int row = tid >> 2, col = (tid & 3) * 16;
  float* gp = outp + ((size_t)(b * Tc + qt * 64 + row)) * TMc + s0 + col;
  #pragma unroll
  for (int j = 0; j < 4; ++j)
    *(f32x4*)(gp + j * 4) = *(const f32x4*)&avg[row * 68 + col + j * 4];
}

// ---------------- fused residual-sum LayerNorm: one block per row of 1024
__global__ __launch_bounds__(256)
void add_ln(const float* __restrict__ in, const float* __restrict__ g,
            const float* __restrict__ bb, float* __restrict__ outf,
            u16* __restrict__ outb)
{
  __shared__ float red1[4];
  __shared__ float red2[4];
  const int tid = threadIdx.x, lane = tid & 63, w = tid >> 6;
  const size_t row = blockIdx.x;
  float4 v = ((const float4*)(in + row * Dc))[tid];
  float s = v.x + v.y + v.z + v.w;
  #pragma unroll
  for (int o = 32; o >= 1; o >>= 1) s += __shfl_xor(s, o);
  if (lane == 0) red1[w] = s;
  __syncthreads();
  s = red1[0] + red1[1] + red1[2] + red1[3];
  const float mean = s * (1.0f / Dc);
  const float dx = v.x - mean, dy = v.y - mean, dz = v.z - mean, dw = v.w - mean;
  float s2 = dx * dx + dy * dy + dz * dz + dw * dw;
  #pragma unroll
  for (int o = 32; o >= 1; o >>= 1) s2 += __shfl_xor(s2, o);
  if (lane == 0) red2[w] = s2;
  __syncthreads();
  s2 = red2[0] + red2[1] + red2[2] + red2[3];
  const float rstd = rsqrtf(s2 * (1.0f / Dc) + 1e-5f);
  const float4 gv = ((const float4*)g)[tid];
  const float4 bv = ((const float4*)bb)[tid];
  float4 o4;
  o4.x = dx * rstd * gv.x + bv.x;
  o4.y = dy * rstd * gv.y + bv.y;
  o4.z = dz * rstd * gv.z + bv.z;
  o4.w = dw * rstd * gv.w + bv.w;
  ((float4*)(outf + row * Dc))[tid] = o4;
  if (outb != nullptr) {
    bf16x4 ob;
    ob[0] = (short)f2bf(o4.x); ob[1] = (short)f2bf(o4.y);
    ob[2] = (short)f2bf(o4.z); ob[3] = (short)f2bf(o4.w);
    *(bf16x4*)(outb + row * Dc + (size_t)tid * 4) = ob;
  }
}

// ---------------- split-K reduce (4 bf16 partials) + bias + residual + LayerNorm
__global__ __launch_bounds__(256)
void add_ln4(const u16* __restrict__ p0, const u16* __restrict__ p1,
             const u16* __restrict__ p2, const u16* __restrict__ p3,
             const float* __restrict__ bias2, const float* __restrict__ resid,
             const float* __restrict__ g, const float* __restrict__ bb,
             float* __restrict__ outf)
{
  __shared__ float red1[4];
  __shared__ float red2[4];
  const int tid = threadIdx.x, lane = tid & 63, w = tid >> 6;
  const size_t row = blockIdx.x;
  const size_t base = row * Dc + (size_t)tid * 4;
  const bf16x4 a0 = *(const bf16x4*)(p0 + base);
  const bf16x4 a1 = *(const bf16x4*)(p1 + base);
  const bf16x4 a2 = *(const bf16x4*)(p2 + base);
  const bf16x4 a3 = *(const bf16x4*)(p3 + base);
  const float4 rv = ((const float4*)(resid + row * Dc))[tid];
  const float4 b2 = ((const float4*)bias2)[tid];
  float4 v;
  v.x = b2f((u16)a0[0]) + b2f((u16)a1[0]) + b2f((u16)a2[0]) + b2f((u16)a3[0]) + b2.x + rv.x;
  v.y = b2f((u16)a0[1]) + b2f((u16)a1[1]) + b2f((u16)a2[1]) + b2f((u16)a3[1]) + b2.y + rv.y;
  v.z = b2f((u16)a0[2]) + b2f((u16)a1[2]) + b2f((u16)a2[2]) + b2f((u16)a3[2]) + b2.z + rv.z;
  v.w = b2f((u16)a0[3]) + b2f((u16)a1[3]) + b2f((u16)a2[3]) + b2f((u16)a3[3]) + b2.w + rv.w;
  float s = v.x + v.y + v.z + v.w;
  #pragma unroll
  for (int o = 32; o >= 1; o >>= 1) s += __shfl_xor(s, o);
  if (lane == 0) red1[w] = s;
  __syncthreads();
  s = red1[0] + red1[1] + red1[2] + red1[3];
  const float mean = s * (1.0f / Dc);
  const float dx = v.x - mean, dy = v.y - mean, dz = v.z - mean, dw = v.w - mean;
  float s2 = dx * dx + dy * dy + dz * dz + dw * dw;
  #pragma unroll
  for (int o = 32; o >= 1; o >>= 1) s2 += __shfl_xor(s2, o);
  if (lane == 0) red2[w] = s2;
  __syncthreads();
  s2 = red2[0] + red2[1] + red2[2] + red2[3];
  const float rstd = rsqrtf(s2 * (1.0f / Dc) + 1e-5f);
  const float4 gv = ((const float4*)g)[tid];
  const float4 bv = ((const float4*)bb)[tid];
  float4 o4;
  o4.x = dx * rstd * gv.x + bv.x;
  o4.y = dy * rstd * gv.y + bv.y;
  o4.z = dz * rstd * gv.z + bv.z;
  o4.w = dw * rstd * gv.w + bv.w;
  ((float4*)(outf + row * Dc))[tid] = o4;
}

extern "C" void kernel_launch(void* const* d_in, const int* in_sizes, int n_in,
                              void* d_out, int out_size, void* d_ws, size_t ws_size,
                              hipStream_t stream)
{
  (void)in_sizes; (void)n_in; (void)out_size; (void)ws_size;
  const float* tgt = (const float*)d_in[0];
  const float* mem = (const float*)d_in[1];
  // weight order: sa q,k,v,o ; ca q,k,v,o ; w1 ; w2
  const float* Wf[10]   = { (const float*)d_in[2],  (const float*)d_in[4],  (const float*)d_in[6],  (const float*)d_in[8],
                            (const float*)d_in[10], (const float*)d_in[12], (const float*)d_in[14], (const float*)d_in[16],
                            (const float*)d_in[18], (const float*)d_in[20] };
  const float* bias_[10]= { (const float*)d_in[3],  (const float*)d_in[5],  (const float*)d_in[7],  (const float*)d_in[9],
                            (const float*)d_in[11], (const float*)d_in[13], (const float*)d_in[15], (const float*)d_in[17],
                            (const float*)d_in[19], (const float*)d_in[21] };
  const float* ln1g = (const float*)d_in[22]; const float* ln1b = (const float*)d_in[23];
  const float* ln2g = (const float*)d_in[24]; const float* ln2b = (const float*)d_in[25];
  const float* ln3g = (const float*)d_in[26]; const float* ln3b = (const float*)d_in[27];

  char* wsp = (char*)d_ws;
  auto alloc = [&](size_t bytes) -> char* {
    char* p = wsp;
    wsp += (bytes + 255) & ~(size_t)255;
    return p;
  };
  // persistent regions
  u16* wT[8];
  for (int i = 0; i < 8; ++i) wT[i] = (u16*)alloc((size_t)Dc * Dc * 2);
  u16* w1T  = (u16*)alloc((size_t)Dc * FFc * 2);
  u16* w2T  = (u16*)alloc((size_t)Dc * FFc * 2);
  u16* xb   = (u16*)alloc((size_t)BT * Dc * 2);
  u16* memb = (u16*)alloc((size_t)BT * Dc * 2);
  u16* qb   = (u16*)alloc((size_t)BT * Dc * 2);
  u16* yb   = (u16*)alloc((size_t)BT * Dc * 2);
  u16* ffb  = (u16*)alloc((size_t)BT * FFc * 2);   // also hosts qkv (sa) then kv (ca)
  float* res = (float*)alloc((size_t)BT * Dc * 4); // also hosts wqkvT concat early
  float* xf  = (float*)alloc((size_t)BT * Dc * 4);
  float* mws = (float*)alloc((size_t)Bc * Hc * Tc * 4);
  float* lws = (float*)alloc((size_t)Bc * Hc * Tc * 4);
  // small persistent bias concats — MUST NOT alias reused regions (R3 lesson)
  float* bqkv = (float*)alloc(3 * Dc * 4);
  float* bkv  = (float*)alloc(2 * Dc * 4);

  // aliases (sequentially dead regions)
  u16* qkv    = ffb;                       // [4096][3072], self-attn phase
  u16* kvb    = ffb;                       // [4096][2048], cross-attn phase
  u16* wqkvT  = (u16*)res;                 // [3072][1024] bf16 (6.3 MB), dead after sa QKV gemm
  // FFN2 split-K bf16 partials (8 MB each) in buffers dead by FFN2 time:
  // qb (last: attn_avg), yb (last: ca o-proj), memb (last: kv gemm), res lo-half (last: add_ln2)
  Ptr4 fp { qb, yb, memb, (u16*)res };

  float* out_x   = (float*)d_out;
  float* out_att = out_x + (size_t)BT * Dc;

  Ptr4 z { nullptr, nullptr, nullptr, nullptr };

  // weights: fp32 [K,N] -> bf16 [N,K]. One launch for all 8 DxD matrices;
  // q,k,v transposed DIRECTLY into the wqkvT concat region (no memcpys).
  {
    P8f S; P8u D;
    for (int i = 0; i < 8; ++i) S.p[i] = Wf[i];
    D.p[0] = wqkvT;               D.p[1] = wqkvT + (size_t)Dc * Dc;
    D.p[2] = wqkvT + (size_t)2 * Dc * Dc;
    for (int i = 3; i < 8; ++i) D.p[i] = wT[i];
    tconv8<<<dim3(16, 16, 8), 256, 0, stream>>>(S, D);
  }
  tconv<<<dim3(FFc / 64, Dc / 64), 256, 0, stream>>>(Wf[8], w1T, Dc, FFc);
  tconv<<<dim3(Dc / 64, FFc / 64), 256, 0, stream>>>(Wf[9], w2T, FFc, Dc);
  cvt_bf16<<<BT * Dc / 4 / 256, 256, 0, stream>>>(tgt, xb, BT * Dc / 4);
  cvt_bf16<<<BT * Dc / 4 / 256, 256, 0, stream>>>(mem, memb, BT * Dc / 4);
  biascat<<<5, 1024, 0, stream>>>(bqkv, bkv, bias_[0], bias_[1], bias_[2],
                                  bias_[5], bias_[6]);

  // 1D grids (in-kernel XCD-chunked grouped remap)
  const int nD    = (Dc / 128) * (BT / 128);        // 256   (narrow, BM=128, DEPTH=2)
  const int nQKVw = (3 * Dc / 128) * (BT / 256);    // 384   (wide,   BM=256, DEPTH=2)
  const int nKVw  = (2 * Dc / 128) * (BT / 256);    // 256   (wide)
  const int nFw   = (FFc / 128) * (BT / 256);       // 512   (wide)
  const int nAtt  = (Tc / 64) * (Bc * Hc);          // 1024  (flash, XCD-chunked 1D)
  const dim3 gAvg(TMc / 64, Tc / 64, Bc);   // (16,16,4) = 1024 blocks

  // ---- self-attention block (fused QKV projection)
  gemm_bt<0, 256, 2><<<nQKVw, 512, 0, stream>>>(xb, wqkvT, bqkv, nullptr, qkv, BT, 3 * Dc, Dc, Dc, z);
  flash_attn<<<nAtt, 256, 0, stream>>>(qkv, qkv + Dc, qkv + 2 * Dc, yb,
                                       nullptr, nullptr, 3 * Dc, 3 * Dc);
  gemm_bt<1, 128, 2><<<nD, 256, 0, stream>>>(yb, wT[3], bias_[3], tgt, res, BT, Dc, Dc, Dc, z);
  add_ln<<<BT, 256, 0, stream>>>(res, ln1g, ln1b, xf, xb);

  // ---- cross-attention block (fused KV projection; + head-averaged probs)
  // wT[6] == wT[5] + Dc*Dc (sequential 2 MiB allocs, 256B-multiple → adjacent),
  // so wT[5] serves as the [2048][1024] fused K|V weight matrix.
  gemm_bt<0, 128, 2><<<nD, 256, 0, stream>>>(xb, wT[4], bias_[4], nullptr, qb, BT, Dc, Dc, Dc, z);
  gemm_bt<0, 256, 2><<<nKVw, 512, 0, stream>>>(memb, wT[5], bkv, nullptr, kvb, BT, 2 * Dc, Dc, Dc, z);
  flash_attn<<<nAtt, 256, 0, stream>>>(qb, kvb, kvb + Dc, yb, mws, lws, Dc, 2 * Dc);
  attn_avg<<<gAvg, 256, 0, stream>>>(qb, kvb, mws, lws, out_att, Dc, 2 * Dc);
  gemm_bt<1, 128, 2><<<nD, 256, 0, stream>>>(yb, wT[7], bias_[7], xf, res, BT, Dc, Dc, Dc, z);
  add_ln<<<BT, 256, 0, stream>>>(res, ln2g, ln2b, xf, xb);

  // ---- FFN block (FFN2 split-K=4 -> 1024 blocks, reduce fused into add_ln4)
  gemm_bt<2, 256, 2><<<nFw, 512, 0, stream>>>(xb,  w1T, bias_[8], nullptr, ffb, BT, FFc, Dc, Dc, z);
  gemm_bt<3, 128, 2><<<dim3(nD, 4), 256, 0, stream>>>(ffb, w2T, nullptr, nullptr, nullptr,
                                                      BT, Dc, FFc, FFc / 4, fp);
  add_ln4<<<BT, 256, 0, stream>>>(fp.p0, fp.p1, fp.p2, fp.p3, bias_[9], xf,
                                  ln3g, ln3b, out_x);
}

// Round 19
// 432.073 us; speedup vs baseline: 1.0061x; 1.0061x over previous
//
#include <hip/hip_runtime.h>
#include <hip/hip_bf16.h>
#include <cstdint>
#include <cstddef>

using u16 = unsigned short;
typedef __attribute__((ext_vector_type(4))) float f32x4;
typedef __attribute__((ext_vector_type(8))) short bf16x8;
typedef __attribute__((ext_vector_type(4))) short bf16x4;

constexpr int Bc = 4, Tc = 1024, TMc = 1024, Dc = 1024, Hc = 16, HSc = 64, FFc = 4096;
constexpr int BT = Bc * Tc;  // 4096 rows
constexpr float C2 = 0.18033688f;   // 0.125 * log2(e) — folded into Q projection (R19)

struct Ptr4 { u16* p0; u16* p1; u16* p2; u16* p3; };
struct P8f  { const float* p[8]; };
struct P8u  { u16* p[8]; };

__device__ __forceinline__ u16 f2bf(float f) {
  union { float f; uint32_t u; } v; v.f = f;
  uint32_t u = v.u;
  u += 0x7fffu + ((u >> 16) & 1u);   // RNE (finite inputs only)
  return (u16)(u >> 16);
}
__device__ __forceinline__ float b2f(u16 u) {
  union { float f; uint32_t u32; } v; v.u32 = (uint32_t)u << 16; return v.f;
}
// pack two floats' high halves (truncating bf16 pair) in ONE v_perm_b32
__device__ __forceinline__ uint32_t pk2(float hi, float lo) {
  union { float f; uint32_t u; } a, b; a.f = hi; b.f = lo;
  return __builtin_amdgcn_perm(a.u, b.u, 0x07060302u);
}

__device__ __forceinline__ bf16x8 cat8(bf16x4 lo, bf16x4 hi) {
  bf16x8 r;
  r[0] = lo[0]; r[1] = lo[1]; r[2] = lo[2]; r[3] = lo[3];
  r[4] = hi[0]; r[5] = hi[1]; r[6] = hi[2]; r[7] = hi[3];
  return r;
}

// async global->LDS, 16B per lane; LDS dest = wave-uniform base + lane*16B (linear)
__device__ __forceinline__ void gload16(const u16* g, u16* l) {
  __builtin_amdgcn_global_load_lds((const __attribute__((address_space(1))) void*)g,
                                   (__attribute__((address_space(3))) void*)l, 16, 0, 0);
}

// ---------------- transpose + fp32->bf16 convert: 8x [1024,1024] in one launch.
// Grid (16,16,8); blockIdx.z selects src/dst (q,k,v land directly in wqkvT).
__global__ __launch_bounds__(256)
void tconv8(P8f S, P8u D)
{
  __shared__ u16 tile[64][65];
  const float* in = S.p[blockIdx.z];
  u16* outp = D.p[blockIdx.z];
  const int tx = threadIdx.x & 15, ty = threadIdx.x >> 4;
  const int kb = blockIdx.y * 64, nb = blockIdx.x * 64;
  #pragma unroll
  for (int i = 0; i < 4; ++i) {
    const int r = ty + i * 16;
    const float4 v = *(const float4*)(in + (size_t)(kb + r) * Dc + nb + tx * 4);
    tile[r][tx * 4 + 0] = f2bf(v.x);
    tile[r][tx * 4 + 1] = f2bf(v.y);
    tile[r][tx * 4 + 2] = f2bf(v.z);
    tile[r][tx * 4 + 3] = f2bf(v.w);
  }
  __syncthreads();
  #pragma unroll
  for (int i = 0; i < 4; ++i) {
    const int n = ty + i * 16;
    bf16x4 o;
    o[0] = (short)tile[tx * 4 + 0][n];
    o[1] = (short)tile[tx * 4 + 1][n];
    o[2] = (short)tile[tx * 4 + 2][n];
    o[3] = (short)tile[tx * 4 + 3][n];
    *(bf16x4*)(outp + (size_t)(nb + n) * Dc + kb + tx * 4) = o;
  }
}

// ---------------- transpose + convert, general shape (w1, w2)
__global__ __launch_bounds__(256)
void tconv(const float* __restrict__ in, u16* __restrict__ outp, int K, int N)
{
  __shared__ u16 tile[64][65];
  const int tx = threadIdx.x & 15, ty = threadIdx.x >> 4;
  const int kb = blockIdx.y * 64, nb = blockIdx.x * 64;
  #pragma unroll
  for (int i = 0; i < 4; ++i) {
    const int r = ty + i * 16;
    const float4 v = *(const float4*)(in + (size_t)(kb + r) * N + nb + tx * 4);
    tile[r][tx * 4 + 0] = f2bf(v.x);
    tile[r][tx * 4 + 1] = f2bf(v.y);
    tile[r][tx * 4 + 2] = f2bf(v.z);
    tile[r][tx * 4 + 3] = f2bf(v.w);
  }
  __syncthreads();
  #pragma unroll
  for (int i = 0; i < 4; ++i) {
    const int n = ty + i * 16;
    bf16x4 o;
    o[0] = (short)tile[tx * 4 + 0][n];
    o[1] = (short)tile[tx * 4 + 1][n];
    o[2] = (short)tile[tx * 4 + 2][n];
    o[3] = (short)tile[tx * 4 + 3][n];
    *(bf16x4*)(outp + (size_t)(nb + n) * K + kb + tx * 4) = o;
  }
}

// ---------------- elementwise fp32 -> bf16
__global__ __launch_bounds__(256)
void cvt_bf16(const float* __restrict__ in, u16* __restrict__ outp, int n4)
{
  const int i = blockIdx.x * 256 + threadIdx.x;
  if (i < n4) {
    const float4 v = ((const float4*)in)[i];
    bf16x4 o;
    o[0] = (short)f2bf(v.x); o[1] = (short)f2bf(v.y);
    o[2] = (short)f2bf(v.z); o[3] = (short)f2bf(v.w);
    ((bf16x4*)outp)[i] = o;
  }
}

// ---------------- bias concats (replaces 5 hipMemcpyAsync graph nodes)
__global__ __launch_bounds__(1024)
void biascat(float* __restrict__ bqkv, float* __restrict__ bkv,
             const float* b0, const float* b1, const float* b2,
             const float* b5, const float* b6)
{
  const int t = threadIdx.x, z = blockIdx.x;
  if (z < 3) {
    const float* s = (z == 0) ? b0 : (z == 1) ? b1 : b2;
    bqkv[z * 1024 + t] = s[t];
  } else {
    const float* s = (z == 3) ? b5 : b6;
    bkv[(z - 3) * 1024 + t] = s[t];
  }
}

// ---------------- GEMM: C[M,N] = A[M,K](bf16) * Bt[N,K](bf16)^T + bias
// Both-sides XOR swizzle + (DEPTH+1)-buffer counted-vmcnt pipeline + XCD-chunked
// grouped-M remap. bf16 outputs use the per-wave LDS-staged coalesced epilogue.
// MODE 0: out bf16 (cols < qcols scaled by C2 — folds softmax scale into Q);
// MODE 1: out f32 + resid; MODE 2: out bf16 + relu;
// MODE 3: split-K bf16 partial — blockIdx.y = sk, K-chunk Kch, out -> P.p[sk].
template<int MODE, int BMv, int DEPTH>
__global__ __launch_bounds__((BMv == 256) ? 512 : 256)
void gemm_bt(const u16* __restrict__ A, const u16* __restrict__ Bt,
             const float* __restrict__ bias, const float* __restrict__ resid,
             void* __restrict__ outp, int M, int N, int K, int Kch, Ptr4 P,
             int qcols)
{
  constexpr int BM = BMv, BN = 128, BK = 32;
  constexpr int NTHR = (BM == 256) ? 512 : 256;
  constexpr int RPC = NTHR / 4;               // rows covered per gload16 call
  constexpr int ACALLS = BM / RPC;            // 2
  constexpr int BCALLS = BN / RPC;            // 1 (wide) or 2 (narrow)
  constexpr int CALLS = ACALLS + BCALLS;      // 3 (wide) or 4 (narrow)
  constexpr int NB = DEPTH + 1;
  __shared__ __align__(16) u16 As[NB][BM * BK];
  __shared__ __align__(16) u16 Bs[NB][BN * BK];
  const int tid = threadIdx.x;
  const int lane = tid & 63, w = tid >> 6;
  const int wr = w >> 1, wc = w & 1;
  const int hi4 = lane >> 4, lr = lane & 15;

  // --- XCD-chunked grouped block remap (requires nwg%8==0 and (M/BM)%8==0)
  const int nwg = gridDim.x;
  const int GX = N / BN;
  const int bid0 = (int)blockIdx.x;
  const int L = (bid0 & 7) * (nwg >> 3) + (bid0 >> 3);
  const int bandw = 8 * GX;
  const int band = L / bandw;
  const int rem = L - band * bandw;
  const int m0 = (band * 8 + (rem & 7)) * BM;
  const int n0 = (rem >> 3) * BN;

  const int k0 = (MODE == 3) ? (int)blockIdx.y * Kch : 0;

  // staging: row = tid>>2, 16B slot = tid&3 (LDS linear);
  // source slot pre-swizzled: LDS slot s of row r holds global slot s^((r>>1)&3).
  const int srow = tid >> 2;
  const int gslot = (tid & 3) ^ ((srow >> 1) & 3);
  const u16* ga = A  + (size_t)(m0 + srow) * K + k0 + gslot * 8;
  const u16* gb = Bt + (size_t)(n0 + srow) * K + k0 + gslot * 8;
  const int wofs = w * 512;
  const int cswz = (lr >> 1) & 3;             // (row>>1)&3 for read rows base+lr

  auto stage = [&](int buf, int kt) {
    #pragma unroll
    for (int j = 0; j < ACALLS; ++j)
      gload16(ga + (size_t)j * RPC * K + kt, &As[buf][j * NTHR * 8 + wofs]);
    #pragma unroll
    for (int j = 0; j < BCALLS; ++j)
      gload16(gb + (size_t)j * RPC * K + kt, &Bs[buf][j * NTHR * 8 + wofs]);
  };

  f32x4 acc[4][4] = {};
  const int nt = Kch / BK;

  #pragma unroll
  for (int p = 0; p < DEPTH; ++p)
    if (p < nt) stage(p % NB, p * BK);

  int cur = 0;
  for (int t = 0; t < nt; ++t) {
    // allowed outstanding after wait = min(DEPTH-1, nt-1-t) * CALLS  (tail-correct)
    {
      const int ahead = nt - 1 - t;
      const int cap = (ahead < DEPTH - 1 ? ahead : DEPTH - 1) * CALLS;
      switch (cap) {
        case 0:  asm volatile("s_waitcnt vmcnt(0)"  ::: "memory"); break;
        case 3:  asm volatile("s_waitcnt vmcnt(3)"  ::: "memory"); break;
        case 4:  asm volatile("s_waitcnt vmcnt(4)"  ::: "memory"); break;
        case 8:  asm volatile("s_waitcnt vmcnt(8)"  ::: "memory"); break;
        default: asm volatile("s_waitcnt vmcnt(12)" ::: "memory"); break;
      }
    }
    __builtin_amdgcn_s_barrier();
    __builtin_amdgcn_sched_barrier(0);

    if (t + DEPTH < nt) {
      int b2 = cur + DEPTH; if (b2 >= NB) b2 -= NB;
      stage(b2, (t + DEPTH) * BK);
    }

    bf16x8 af[4], bfr[4];
    #pragma unroll
    for (int mb = 0; mb < 4; ++mb)
      af[mb] = *(const bf16x8*)&As[cur][(wr * 64 + mb * 16 + lr) * BK + (hi4 ^ cswz) * 8];
    #pragma unroll
    for (int nb = 0; nb < 4; ++nb)
      bfr[nb] = *(const bf16x8*)&Bs[cur][(wc * 64 + nb * 16 + lr) * BK + (hi4 ^ cswz) * 8];
    #pragma unroll
    for (int mb = 0; mb < 4; ++mb)
      #pragma unroll
      for (int nb = 0; nb < 4; ++nb)
        acc[mb][nb] = __builtin_amdgcn_mfma_f32_16x16x32_bf16(af[mb], bfr[nb], acc[mb][nb], 0, 0, 0);

    ++cur; if (cur == NB) cur = 0;
  }

  const int orow = m0 + wr * 64 + 4 * hi4;
  const int ocol = n0 + wc * 64 + lr;

  if (MODE == 1) {
    #pragma unroll
    for (int nb = 0; nb < 4; ++nb) {
      const int c = ocol + nb * 16;
      const float bv = bias ? bias[c] : 0.0f;
      #pragma unroll
      for (int mb = 0; mb < 4; ++mb) {
        #pragma unroll
        for (int r = 0; r < 4; ++r) {
          const size_t idx = (size_t)(orow + mb * 16 + r) * N + c;
          ((float*)outp)[idx] = acc[mb][nb][r] + bv + resid[idx];
        }
      }
    }
  } else {
    // bf16 epilogue: per-wave LDS strip (16x68 u16) in Bs, coalesced 16B stores.
    __syncthreads();                     // all waves done with pipeline LDS reads
    u16* eb = &Bs[0][0] + w * 1088;      // 16*68 = 1088 u16 per wave (8*1088 <= 12288)
    u16* pout_;
    if (MODE == 3) {
      const int sk = blockIdx.y;
      pout_ = (sk == 0) ? P.p0 : (sk == 1) ? P.p1 : (sk == 2) ? P.p2 : P.p3;
    } else {
      pout_ = (u16*)outp;
    }
    const int r2 = lane >> 3;            // 0..7
    const int c2 = (lane & 7) * 8;       // 16B chunk
    #pragma unroll
    for (int mb = 0; mb < 4; ++mb) {
      #pragma unroll
      for (int nb = 0; nb < 4; ++nb) {
        const int c = ocol + nb * 16;
        const float bv = (MODE != 3 && bias) ? bias[c] : 0.0f;
        const float csc = (MODE == 0 && c < qcols) ? C2 : 1.0f;
        #pragma unroll
        for (int r = 0; r < 4; ++r) {
          float v = (acc[mb][nb][r] + bv) * csc;
          if (MODE == 2) v = fmaxf(v, 0.0f);
          eb[(4 * hi4 + r) * 68 + nb * 16 + lr] = f2bf(v);
        }
      }
      // same-wave DS ops are in-order; read back coalesced and store full sectors
      #pragma unroll
      for (int pass = 0; pass < 2; ++pass) {
        const int rr = pass * 8 + r2;
        const bf16x8 vv = *(const bf16x8*)&eb[rr * 68 + c2];
        *(bf16x8*)&pout_[(size_t)(m0 + wr * 64 + mb * 16 + rr) * N + n0 + wc * 64 + c2] = vv;
      }
    }
  }
}

// ---------------- flash attention, swapped QK^T. 1D grid (1024 blocks),
// XCD-chunked remap (R18: FETCH 70->12 MB). Double-buffered K/V LDS with T14
// async split; V write vectorized + XOR swizzle; T13 defer-max; exp2-domain
// softmax with scale pre-folded into Q (R19: logits arrive in log2 domain);
// v_perm P pack.
__global__ __launch_bounds__(256)
void flash_attn(const u16* __restrict__ Q, const u16* __restrict__ Kb,
                const u16* __restrict__ Vb, u16* __restrict__ Y,
                float* __restrict__ Mout, float* __restrict__ Lout,
                int qstr, int kstr)
{
  constexpr int LDK = 72;
  __shared__ __align__(16) u16 Ks[2][64 * LDK];   // [key][hs]
  __shared__ __align__(16) u16 Vt[2][64 * LDK];   // [d][key ^ swz]
  const int tid = threadIdx.x, lane = tid & 63, w = tid >> 6;
  const int hi4 = lane >> 4, lr = lane & 15;
  // XCD-chunked remap: nwg=1024; chunk of 128 per XCD = 8 bh-groups x 16 qt
  const int bid0 = (int)blockIdx.x;
  const int L = (bid0 & 7) * 128 + (bid0 >> 3);
  const int bh = L >> 4, qt = L & 15;
  const int b = bh >> 4, h = bh & 15;
  const int q0 = qt * 64 + w * 16;

  bf16x8 qf[2];
  {
    const u16* qp = Q + ((size_t)(b * Tc + q0 + lr)) * qstr + h * HSc;
    #pragma unroll
    for (int ks = 0; ks < 2; ++ks)
      qf[ks] = cat8(*(const bf16x4*)(qp + ks * 32 + 4 * hi4),
                    *(const bf16x4*)(qp + ks * 32 + 16 + 4 * hi4));
  }

  float m_run = -1e30f, l_run = 0.0f;   // m_run in log2 domain
  f32x4 o[4] = {};  // O[q=4*hi4+r][d = nb*16+lr]

  const int krow = tid >> 3, kcol = (tid & 7) * 8;
  const int s4 = (tid >> 4) * 4;     // 4 consecutive keys per thread
  const int d4 = (tid & 15) * 4;     // 4 consecutive d per thread (coalesced loads)

  const u16* kbase = Kb + ((size_t)(b * TMc + krow)) * kstr + h * HSc + kcol;
  const u16* vbase = Vb + ((size_t)(b * TMc + s4)) * kstr + h * HSc + d4;

  bf16x8 kreg0, kreg1;
  bf16x4 vreg[4];

  auto loadch = [&](int s0) {
    const u16* kp = kbase + (size_t)s0 * kstr;
    kreg0 = *(const bf16x8*)kp;
    kreg1 = *(const bf16x8*)(kp + (size_t)32 * kstr);
    const u16* vp = vbase + (size_t)s0 * kstr;
    #pragma unroll
    for (int j = 0; j < 4; ++j)
      vreg[j] = *(const bf16x4*)(vp + (size_t)j * kstr);
  };
  auto writech = [&](int buf) {
    *(bf16x8*)&Ks[buf][krow * LDK + kcol]        = kreg0;
    *(bf16x8*)&Ks[buf][(krow + 32) * LDK + kcol] = kreg1;
    #pragma unroll
    for (int i = 0; i < 4; ++i) {
      bf16x4 tr;
      tr[0] = vreg[0][i]; tr[1] = vreg[1][i]; tr[2] = vreg[2][i]; tr[3] = vreg[3][i];
      *(bf16x4*)&Vt[buf][(d4 + i) * LDK + (s4 ^ d4)] = tr;
    }
  };

  loadch(0);
  writech(0);

  constexpr int NT = TMc / 64;
  for (int t = 0; t < NT; ++t) {
    const int cur = t & 1;
    __syncthreads();                       // buf[cur] fully written by all waves
    if (t + 1 < NT) loadch((t + 1) * 64);  // global loads in flight during compute

    // St = K * Q^T -> St[key = kb2*16 + 4*hi4 + r][q = lr]; already log2-domain
    f32x4 st[4];
    #pragma unroll
    for (int kb2 = 0; kb2 < 4; ++kb2) {
      f32x4 a = {};
      #pragma unroll
      for (int ks = 0; ks < 2; ++ks) {
        const u16* p = &Ks[cur][(kb2 * 16 + lr) * LDK + ks * 32 + 4 * hi4];
        bf16x8 kf = cat8(*(const bf16x4*)p, *(const bf16x4*)(p + 16));
        a = __builtin_amdgcn_mfma_f32_16x16x32_bf16(kf, qf[ks], a, 0, 0, 0);
      }
      st[kb2] = a;
    }

    float cmax = -1e30f;
    #pragma unroll
    for (int kb2 = 0; kb2 < 4; ++kb2)
      cmax = fmaxf(cmax, fmaxf(fmaxf(st[kb2][0], st[kb2][1]),
                               fmaxf(st[kb2][2], st[kb2][3])));
    cmax = fmaxf(cmax, __shfl_xor(cmax, 16));
    cmax = fmaxf(cmax, __shfl_xor(cmax, 32));

    // T13 defer-max (THR = 8 nats = 11.5416 in log2 domain), wave-uniform
    const bool need = !__all(cmax - m_run <= 11.5416f);
    float m_new = m_run, sc = 1.0f;
    if (need) {
      m_new = fmaxf(m_run, cmax);
      sc = exp2f(m_run - m_new);
    }
    float psum = 0.0f;
    #pragma unroll
    for (int kb2 = 0; kb2 < 4; ++kb2)
      #pragma unroll
      for (int r = 0; r < 4; ++r) {
        const float e = exp2f(st[kb2][r] - m_new);
        st[kb2][r] = e;
        psum += e;
      }
    psum += __shfl_xor(psum, 16);
    psum += __shfl_xor(psum, 32);
    if (need) {
      l_run = l_run * sc + psum;
      #pragma unroll
      for (int r = 0; r < 4; ++r) {
        const float osc = __shfl(sc, 4 * hi4 + r);
        #pragma unroll
        for (int nb = 0; nb < 4; ++nb) o[nb][r] *= osc;
      }
    } else {
      l_run += psum;
    }
    m_run = m_new;

    bf16x8 pa[2];
    #pragma unroll
    for (int ks = 0; ks < 2; ++ks) {
      union { bf16x8 v; uint32_t u[4]; } pw;
      pw.u[0] = pk2(st[2 * ks + 0][1], st[2 * ks + 0][0]);
      pw.u[1] = pk2(st[2 * ks + 0][3], st[2 * ks + 0][2]);
      pw.u[2] = pk2(st[2 * ks + 1][1], st[2 * ks + 1][0]);
      pw.u[3] = pk2(st[2 * ks + 1][3], st[2 * ks + 1][2]);
      pa[ks] = pw.v;
    }
    #pragma unroll
    for (int nb = 0; nb < 4; ++nb) {
      const int row = nb * 16 + lr;
      const int g = 4 * (row >> 2);
      #pragma unroll
      for (int ks = 0; ks < 2; ++ks) {
        const int c0 = (ks * 32 + 4 * hi4) ^ g;
        const int c1 = (ks * 32 + 16 + 4 * hi4) ^ g;
        bf16x8 vf = cat8(*(const bf16x4*)&Vt[cur][row * LDK + c0],
                         *(const bf16x4*)&Vt[cur][row * LDK + c1]);
        o[nb] = __builtin_amdgcn_mfma_f32_16x16x32_bf16(pa[ks], vf, o[nb], 0, 0, 0);
      }
    }

    if (t + 1 < NT) writech(cur ^ 1);      // lands before next barrier
  }

  #pragma unroll
  for (int r = 0; r < 4; ++r) {
    const float li = 1.0f / __shfl(l_run, 4 * hi4 + r);
    const size_t yr = ((size_t)(b * Tc + q0 + 4 * hi4 + r)) * Dc + h * HSc;
    #pragma unroll
    for (int nb = 0; nb < 4; ++nb)
      Y[yr + nb * 16 + lr] = f2bf(o[nb][r] * li);
  }
  if (Mout != nullptr && lane < 16) {
    Mout[(size_t)bh * Tc + q0 + lr] = m_run;   // log2-domain
    Lout[(size_t)bh * Tc + q0 + lr] = l_run;
  }
}

// ---------------- cross-attn prob average over heads.
// Grid: (TMc/64, Tc/64, Bc) — 1024 blocks; double-buffered async K staging +
// both-sides XOR swizzle. Q pre-scaled by C2 (logits log2-domain); mws log2-domain.
__global__ __launch_bounds__(256)
void attn_avg(const u16* __restrict__ Q, const u16* __restrict__ Kb,
              const float* __restrict__ Mws, const float* __restrict__ Lws,
              float* __restrict__ outp, int qstr, int kstr)
{
  __shared__ __align__(16) u16 Ks[2][64 * 64];
  __shared__ __align__(16) float avg[64 * 68];
  const int tid = threadIdx.x, lane = tid & 63, w = tid >> 6;
  const int hi4 = lane >> 4, lr = lane & 15;
  const int b = blockIdx.z, qt = blockIdx.y, scn = blockIdx.x;
  const int q0 = qt * 64 + w * 16;
  const int s0 = scn * 64;

  const int srow = w * 8 + (lane >> 3);
  const int scol = ((lane & 7) ^ (lane >> 3)) * 8;
  const u16* kg = Kb + ((size_t)(b * TMc + s0 + srow)) * kstr + scol;
  const size_t skip32 = (size_t)32 * kstr;

  auto stage = [&](int buf, int h) {
    const u16* g = kg + h * HSc;
    gload16(g,          &Ks[buf][w * 512]);
    gload16(g + skip32, &Ks[buf][2048 + w * 512]);
  };

  float acc[4][4] = {};
  const int rsw = lr & 7;

  stage(0, 0);
  #pragma unroll 1
  for (int h = 0; h < Hc; ++h) {
    const int cur = h & 1;
    __syncthreads();
    if (h + 1 < Hc) stage(cur ^ 1, h + 1);

    const u16* qp = Q + ((size_t)(b * Tc + q0 + lr)) * qstr + h * HSc;
    const bf16x8 qf0 = *(const bf16x8*)(qp + 8 * hi4);
    const bf16x8 qf1 = *(const bf16x8*)(qp + 32 + 8 * hi4);
    const float mh2 = Mws[(size_t)(b * Hc + h) * Tc + q0 + lr];   // log2-domain
    const float li = 1.0f / Lws[(size_t)(b * Hc + h) * Tc + q0 + lr];

    #pragma unroll
    for (int kb2 = 0; kb2 < 4; ++kb2) {
      const int row = kb2 * 16 + lr;
      const bf16x8 kf0 = *(const bf16x8*)&Ks[cur][row * 64 + ((hi4     ) ^ rsw) * 8];
      const bf16x8 kf1 = *(const bf16x8*)&Ks[cur][row * 64 + ((hi4 + 4) ^ rsw) * 8];
      f32x4 a = {};
      a = __builtin_amdgcn_mfma_f32_16x16x32_bf16(kf0, qf0, a, 0, 0, 0);
      a = __builtin_amdgcn_mfma_f32_16x16x32_bf16(kf1, qf1, a, 0, 0, 0);
      #pragma unroll
      for (int r = 0; r < 4; ++r)
        acc[kb2][r] += exp2f(a[r] - mh2) * li;
    }
  }

  __syncthreads();
  #pragma unroll
  for (int kb2 = 0; kb2 < 4; ++kb2)
    #pragma unroll
    for (int r = 0; r < 4; ++r)
      avg[(w * 16 + lr) * 68 + kb2 * 16 + 4 * hi4 + r] = acc[kb2][r] * (1.0f / Hc);
  __syncthreads();
  const int row = tid >> 2, col = (tid & 3) * 16;
  float* gp = outp + ((size_t)(b * Tc + qt * 64 + row)) * TMc + s0 + col;
  #pragma unroll
  for (int j = 0; j < 4; ++j)
    *(f32x4*)(gp + j * 4) = *(const f32x4*)&avg[row * 68 + col + j * 4];
}

// ---------------- fused residual-sum LayerNorm: one block per row of 1024
__global__ __launch_bounds__(256)
void add_ln(const float* __restrict__ in, const float* __restrict__ g,
            const float* __restrict__ bb, float* __restrict__ outf,
            u16* __restrict__ outb)
{
  __shared__ float red1[4];
  __shared__ float red2[4];
  const int tid = threadIdx.x, lane = tid & 63, w = tid >> 6;
  const size_t row = blockIdx.x;
  float4 v = ((const float4*)(in + row * Dc))[tid];
  float s = v.x + v.y + v.z + v.w;
  #pragma unroll
  for (int o = 32; o >= 1; o >>= 1) s += __shfl_xor(s, o);
  if (lane == 0) red1[w] = s;
  __syncthreads();
  s = red1[0] + red1[1] + red1[2] + red1[3];
  const float mean = s * (1.0f / Dc);
  const float dx = v.x - mean, dy = v.y - mean, dz = v.z - mean, dw = v.w - mean;
  float s2 = dx * dx + dy * dy + dz * dz + dw * dw;
  #pragma unroll
  for (int o = 32; o >= 1; o >>= 1) s2 += __shfl_xor(s2, o);
  if (lane == 0) red2[w] = s2;
  __syncthreads();
  s2 = red2[0] + red2[1] + red2[2] + red2[3];
  const float rstd = rsqrtf(s2 * (1.0f / Dc) + 1e-5f);
  const float4 gv = ((const float4*)g)[tid];
  const float4 bv = ((const float4*)bb)[tid];
  float4 o4;
  o4.x = dx * rstd * gv.x + bv.x;
  o4.y = dy * rstd * gv.y + bv.y;
  o4.z = dz * rstd * gv.z + bv.z;
  o4.w = dw * rstd * gv.w + bv.w;
  ((float4*)(outf + row * Dc))[tid] = o4;
  if (outb != nullptr) {
    bf16x4 ob;
    ob[0] = (short)f2bf(o4.x); ob[1] = (short)f2bf(o4.y);
    ob[2] = (short)f2bf(o4.z); ob[3] = (short)f2bf(o4.w);
    *(bf16x4*)(outb + row * Dc + (size_t)tid * 4) = ob;
  }
}

// ---------------- split-K reduce (4 bf16 partials) + bias + residual + LayerNorm
__global__ __launch_bounds__(256)
void add_ln4(const u16* __restrict__ p0, const u16* __restrict__ p1,
             const u16* __restrict__ p2, const u16* __restrict__ p3,
             const float* __restrict__ bias2, const float* __restrict__ resid,
             const float* __restrict__ g, const float* __restrict__ bb,
             float* __restrict__ outf)
{
  __shared__ float red1[4];
  __shared__ float red2[4];
  const int tid = threadIdx.x, lane = tid & 63, w = tid >> 6;
  const size_t row = blockIdx.x;
  const size_t base = row * Dc + (size_t)tid * 4;
  const bf16x4 a0 = *(const bf16x4*)(p0 + base);
  const bf16x4 a1 = *(const bf16x4*)(p1 + base);
  const bf16x4 a2 = *(const bf16x4*)(p2 + base);
  const bf16x4 a3 = *(const bf16x4*)(p3 + base);
  const float4 rv = ((const float4*)(resid + row * Dc))[tid];
  const float4 b2 = ((const float4*)bias2)[tid];
  float4 v;
  v.x = b2f((u16)a0[0]) + b2f((u16)a1[0]) + b2f((u16)a2[0]) + b2f((u16)a3[0]) + b2.x + rv.x;
  v.y = b2f((u16)a0[1]) + b2f((u16)a1[1]) + b2f((u16)a2[1]) + b2f((u16)a3[1]) + b2.y + rv.y;
  v.z = b2f((u16)a0[2]) + b2f((u16)a1[2]) + b2f((u16)a2[2]) + b2f((u16)a3[2]) + b2.z + rv.z;
  v.w = b2f((u16)a0[3]) + b2f((u16)a1[3]) + b2f((u16)a2[3]) + b2f((u16)a3[3]) + b2.w + rv.w;
  float s = v.x + v.y + v.z + v.w;
  #pragma unroll
  for (int o = 32; o >= 1; o >>= 1) s += __shfl_xor(s, o);
  if (lane == 0) red1[w] = s;
  __syncthreads();
  s = red1[0] + red1[1] + red1[2] + red1[3];
  const float mean = s * (1.0f / Dc);
  const float dx = v.x - mean, dy = v.y - mean, dz = v.z - mean, dw = v.w - mean;
  float s2 = dx * dx + dy * dy + dz * dz + dw * dw;
  #pragma unroll
  for (int o = 32; o >= 1; o >>= 1) s2 += __shfl_xor(s2, o);
  if (lane == 0) red2[w] = s2;
  __syncthreads();
  s2 = red2[0] + red2[1] + red2[2] + red2[3];
  const float rstd = rsqrtf(s2 * (1.0f / Dc) + 1e-5f);
  const float4 gv = ((const float4*)g)[tid];
  const float4 bv = ((const float4*)bb)[tid];
  float4 o4;
  o4.x = dx * rstd * gv.x + bv.x;
  o4.y = dy * rstd * gv.y + bv.y;
  o4.z = dz * rstd * gv.z + bv.z;
  o4.w = dw * rstd * gv.w + bv.w;
  ((float4*)(outf + row * Dc))[tid] = o4;
}

extern "C" void kernel_launch(void* const* d_in, const int* in_sizes, int n_in,
                              void* d_out, int out_size, void* d_ws, size_t ws_size,
                              hipStream_t stream)
{
  (void)in_sizes; (void)n_in; (void)out_size; (void)ws_size;
  const float* tgt = (const float*)d_in[0];
  const float* mem = (const float*)d_in[1];
  // weight order: sa q,k,v,o ; ca q,k,v,o ; w1 ; w2
  const float* Wf[10]   = { (const float*)d_in[2],  (const float*)d_in[4],  (const float*)d_in[6],  (const float*)d_in[8],
                            (const float*)d_in[10], (const float*)d_in[12], (const float*)d_in[14], (const float*)d_in[16],
                            (const float*)d_in[18], (const float*)d_in[20] };
  const float* bias_[10]= { (const float*)d_in[3],  (const float*)d_in[5],  (const float*)d_in[7],  (const float*)d_in[9],
                            (const float*)d_in[11], (const float*)d_in[13], (const float*)d_in[15], (const float*)d_in[17],
                            (const float*)d_in[19], (const float*)d_in[21] };
  const float* ln1g = (const float*)d_in[22]; const float* ln1b = (const float*)d_in[23];
  const float* ln2g = (const float*)d_in[24]; const float* ln2b = (const float*)d_in[25];
  const float* ln3g = (const float*)d_in[26]; const float* ln3b = (const float*)d_in[27];

  char* wsp = (char*)d_ws;
  auto alloc = [&](size_t bytes) -> char* {
    char* p = wsp;
    wsp += (bytes + 255) & ~(size_t)255;
    return p;
  };
  // persistent regions
  u16* wT[8];
  for (int i = 0; i < 8; ++i) wT[i] = (u16*)alloc((size_t)Dc * Dc * 2);
  u16* w1T  = (u16*)alloc((size_t)Dc * FFc * 2);
  u16* w2T  = (u16*)alloc((size_t)Dc * FFc * 2);
  u16* xb   = (u16*)alloc((size_t)BT * Dc * 2);
  u16* memb = (u16*)alloc((size_t)BT * Dc * 2);
  u16* qb   = (u16*)alloc((size_t)BT * Dc * 2);
  u16* yb   = (u16*)alloc((size_t)BT * Dc * 2);
  u16* ffb  = (u16*)alloc((size_t)BT * FFc * 2);   // also hosts qkv (sa) then kv (ca)
  float* res = (float*)alloc((size_t)BT * Dc * 4); // also hosts wqkvT concat early
  float* xf  = (float*)alloc((size_t)BT * Dc * 4);
  float* mws = (float*)alloc((size_t)Bc * Hc * Tc * 4);
  float* lws = (float*)alloc((size_t)Bc * Hc * Tc * 4);
  // small persistent bias concats — MUST NOT alias reused regions (R3 lesson)
  float* bqkv = (float*)alloc(3 * Dc * 4);
  float* bkv  = (float*)alloc(2 * Dc * 4);

  // aliases (sequentially dead regions)
  u16* qkv    = ffb;                       // [4096][3072], self-attn phase
  u16* kvb    = ffb;                       // [4096][2048], cross-attn phase
  u16* wqkvT  = (u16*)res;                 // [3072][1024] bf16 (6.3 MB), dead after sa QKV gemm
  // FFN2 split-K bf16 partials (8 MB each) in buffers dead by FFN2 time:
  // qb (last: attn_avg), yb (last: ca o-proj), memb (last: kv gemm), res lo-half (last: add_ln2)
  Ptr4 fp { qb, yb, memb, (u16*)res };

  float* out_x   = (float*)d_out;
  float* out_att = out_x + (size_t)BT * Dc;

  Ptr4 z { nullptr, nullptr, nullptr, nullptr };

  // weights: fp32 [K,N] -> bf16 [N,K]. One launch for all 8 DxD matrices;
  // q,k,v transposed DIRECTLY into the wqkvT concat region (no memcpys).
  {
    P8f S; P8u D;
    for (int i = 0; i < 8; ++i) S.p[i] = Wf[i];
    D.p[0] = wqkvT;               D.p[1] = wqkvT + (size_t)Dc * Dc;
    D.p[2] = wqkvT + (size_t)2 * Dc * Dc;
    for (int i = 3; i < 8; ++i) D.p[i] = wT[i];
    tconv8<<<dim3(16, 16, 8), 256, 0, stream>>>(S, D);
  }
  tconv<<<dim3(FFc / 64, Dc / 64), 256, 0, stream>>>(Wf[8], w1T, Dc, FFc);
  tconv<<<dim3(Dc / 64, FFc / 64), 256, 0, stream>>>(Wf[9], w2T, FFc, Dc);
  cvt_bf16<<<BT * Dc / 4 / 256, 256, 0, stream>>>(tgt, xb, BT * Dc / 4);
  cvt_bf16<<<BT * Dc / 4 / 256, 256, 0, stream>>>(mem, memb, BT * Dc / 4);
  biascat<<<5, 1024, 0, stream>>>(bqkv, bkv, bias_[0], bias_[1], bias_[2],
                                  bias_[5], bias_[6]);

  // 1D grids (in-kernel XCD-chunked grouped remap)
  const int nD    = (Dc / 128) * (BT / 128);        // 256   (narrow, BM=128, DEPTH=2)
  const int nQKVw = (3 * Dc / 128) * (BT / 256);    // 384   (wide,   BM=256, DEPTH=2)
  const int nKVw  = (2 * Dc / 128) * (BT / 256);    // 256   (wide)
  const int nFw   = (FFc / 128) * (BT / 256);       // 512   (wide)
  const int nAtt  = (Tc / 64) * (Bc * Hc);          // 1024  (flash, XCD-chunked 1D)
  const dim3 gAvg(TMc / 64, Tc / 64, Bc);   // (16,16,4) = 1024 blocks

  // ---- self-attention block (fused QKV projection; Q cols pre-scaled by C2)
  gemm_bt<0, 256, 2><<<nQKVw, 512, 0, stream>>>(xb, wqkvT, bqkv, nullptr, qkv, BT, 3 * Dc, Dc, Dc, z, Dc);
  flash_attn<<<nAtt, 256, 0, stream>>>(qkv, qkv + Dc, qkv + 2 * Dc, yb,
                                       nullptr, nullptr, 3 * Dc, 3 * Dc);
  gemm_bt<1, 128, 2><<<nD, 256, 0, stream>>>(yb, wT[3], bias_[3], tgt, res, BT, Dc, Dc, Dc, z, 0);
  add_ln<<<BT, 256, 0, stream>>>(res, ln1g, ln1b, xf, xb);

  // ---- cross-attention block (fused KV projection; + head-averaged probs)
  // wT[6] == wT[5] + Dc*Dc (sequential 2 MiB allocs, 256B-multiple → adjacent),
  // so wT[5] serves as the [2048][1024] fused K|V weight matrix.
  gemm_bt<0, 128, 2><<<nD, 256, 0, stream>>>(xb, wT[4], bias_[4], nullptr, qb, BT, Dc, Dc, Dc, z, Dc);
  gemm_bt<0, 256, 2><<<nKVw, 512, 0, stream>>>(memb, wT[5], bkv, nullptr, kvb, BT, 2 * Dc, Dc, Dc, z, 0);
  flash_attn<<<nAtt, 256, 0, stream>>>(qb, kvb, kvb + Dc, yb, mws, lws, Dc, 2 * Dc);
  attn_avg<<<gAvg, 256, 0, stream>>>(qb, kvb, mws, lws, out_att, Dc, 2 * Dc);
  gemm_bt<1, 128, 2><<<nD, 256, 0, stream>>>(yb, wT[7], bias_[7], xf, res, BT, Dc, Dc, Dc, z, 0);
  add_ln<<<BT, 256, 0, stream>>>(res, ln2g, ln2b, xf, xb);

  // ---- FFN block (FFN2 split-K=4 -> 1024 blocks, reduce fused into add_ln4)
  gemm_bt<2, 256, 2><<<nFw, 512, 0, stream>>>(xb,  w1T, bias_[8], nullptr, ffb, BT, FFc, Dc, Dc, z, 0);
  gemm_bt<3, 128, 2><<<dim3(nD, 4), 256, 0, stream>>>(ffb, w2T, nullptr, nullptr, nullptr,
                                                      BT, Dc, FFc, FFc / 4, fp, 0);
  add_ln4<<<BT, 256, 0, stream>>>(fp.p0, fp.p1, fp.p2, fp.p3, bias_[9], xf,
                                  ln3g, ln3b, out_x);
}